// Round 2
// baseline (826.083 us; speedup 1.0000x reference)
//
#include <hip/hip_runtime.h>

#define NN 8192

// --- Kernel 1: z[j] = input[j] (workspace is poisoned each launch) ---
__global__ __launch_bounds__(256) void init_z(const float* __restrict__ input,
                                              float* __restrict__ z) {
    int j = blockIdx.x * 256 + threadIdx.x;
    z[j] = input[j];
}

// --- Kernel 2: partial matvec: z[j] += sum_i yin[i]*(w[i,j] + alpha[i,j]*hebb[i,j]) ---
// grid = (2 col-tiles, 1024 row-groups), block = 256 threads.
// Each block covers 4096 cols (16 KB contiguous per row per matrix) x 8 rows.
// Wide contiguous bursts per matrix stream -> DRAM page efficiency; 2048 blocks
// = 8 blocks/CU = 32-wave residency cap.
__global__ __launch_bounds__(256) void matvec_partial(
    const float* __restrict__ yin,
    const float* __restrict__ w,
    const float* __restrict__ alpha,
    const float* __restrict__ hebb,
    float* __restrict__ z)
{
    const int j0 = blockIdx.x * 4096 + threadIdx.x * 4;  // thread's first col
    const int i0 = blockIdx.y * 8;

    float4 s[4];
#pragma unroll
    for (int c = 0; c < 4; ++c) s[c] = make_float4(0.f, 0.f, 0.f, 0.f);

    for (int r = 0; r < 8; ++r) {
        const int i = i0 + r;
        const float y = yin[i];  // uniform per block iter -> scalar load
        const size_t base = (size_t)i * NN + (size_t)j0;

        float4 wv[4], av[4], hv[4];
        // Cluster loads per matrix: 4 back-to-back float4 loads = 16 KB/row
        // across the block from ONE stream before switching streams.
#pragma unroll
        for (int c = 0; c < 4; ++c) wv[c] = *(const float4*)(w + base + c * 1024);
#pragma unroll
        for (int c = 0; c < 4; ++c) av[c] = *(const float4*)(alpha + base + c * 1024);
#pragma unroll
        for (int c = 0; c < 4; ++c) hv[c] = *(const float4*)(hebb + base + c * 1024);

#pragma unroll
        for (int c = 0; c < 4; ++c) {
            s[c].x = fmaf(y, fmaf(av[c].x, hv[c].x, wv[c].x), s[c].x);
            s[c].y = fmaf(y, fmaf(av[c].y, hv[c].y, wv[c].y), s[c].y);
            s[c].z = fmaf(y, fmaf(av[c].z, hv[c].z, wv[c].z), s[c].z);
            s[c].w = fmaf(y, fmaf(av[c].w, hv[c].w, wv[c].w), s[c].w);
        }
    }

#pragma unroll
    for (int c = 0; c < 4; ++c) {
        atomicAdd(&z[j0 + c * 1024 + 0], s[c].x);
        atomicAdd(&z[j0 + c * 1024 + 1], s[c].y);
        atomicAdd(&z[j0 + c * 1024 + 2], s[c].z);
        atomicAdd(&z[j0 + c * 1024 + 3], s[c].w);
    }
}

// --- Kernel 3: yout[j] = tanh(z[j]) ---
__global__ __launch_bounds__(256) void tanh_k(const float* __restrict__ z,
                                              float* __restrict__ yout) {
    int j = blockIdx.x * 256 + threadIdx.x;
    yout[j] = tanhf(z[j]);
}

// --- Kernel 4: hebb_new[i,j] = (1-eta)*hebb[i,j] + eta*yin[i]*yout[j] ---
// 16384 blocks x 256 threads, 4 float4 per thread (coalesced within block)
__global__ __launch_bounds__(256) void hebb_update(
    const float* __restrict__ hebb,
    const float* __restrict__ yin,
    const float* __restrict__ yout,
    const float* __restrict__ eta_p,
    float* __restrict__ hebb_out)
{
    const float eta = eta_p[0];
    const float om = 1.0f - eta;
    const size_t f0 = (size_t)blockIdx.x * 1024 + threadIdx.x;
#pragma unroll
    for (int k = 0; k < 4; ++k) {
        const size_t f = f0 + (size_t)k * 256;   // float4 index
        const size_t i = f >> 11;                // row (2048 float4 per row)
        const size_t j = (f & 2047) * 4;         // col
        const float ye = eta * yin[i];
        const float4 h  = *(const float4*)(hebb + i * NN + j);
        const float4 yo = *(const float4*)(yout + j);
        float4 o;
        o.x = fmaf(om, h.x, ye * yo.x);
        o.y = fmaf(om, h.y, ye * yo.y);
        o.z = fmaf(om, h.z, ye * yo.z);
        o.w = fmaf(om, h.w, ye * yo.w);
        *(float4*)(hebb_out + i * NN + j) = o;
    }
}

extern "C" void kernel_launch(void* const* d_in, const int* in_sizes, int n_in,
                              void* d_out, int out_size, void* d_ws, size_t ws_size,
                              hipStream_t stream) {
    const float* input = (const float*)d_in[0];   // [1, N]
    const float* yin   = (const float*)d_in[1];   // [1, N]
    const float* hebb  = (const float*)d_in[2];   // [N, N]
    const float* w     = (const float*)d_in[3];   // [N, N]
    const float* alpha = (const float*)d_in[4];   // [N, N]
    const float* eta   = (const float*)d_in[5];   // [1]

    float* yout_out = (float*)d_out;              // first N floats
    float* hebb_out = yout_out + NN;              // next N*N floats
    float* z = (float*)d_ws;                      // N floats scratch

    init_z<<<NN / 256, 256, 0, stream>>>(input, z);
    matvec_partial<<<dim3(2, 1024), 256, 0, stream>>>(yin, w, alpha, hebb, z);
    tanh_k<<<NN / 256, 256, 0, stream>>>(z, yout_out);
    hebb_update<<<(NN * (size_t)NN) / 4096, 256, 0, stream>>>(hebb, yin, yout_out, eta, hebb_out);
}

// Round 3
// 791.849 us; speedup vs baseline: 1.0432x; 1.0432x over previous
//
#include <hip/hip_runtime.h>

#define NN 8192

typedef float v4f __attribute__((ext_vector_type(4)));

__device__ __forceinline__ v4f nt_load4(const float* p) {
    return __builtin_nontemporal_load((const v4f*)p);
}

// --- Kernel 1: z[j] = input[j] (workspace is poisoned each launch) ---
__global__ __launch_bounds__(256) void init_z(const float* __restrict__ input,
                                              float* __restrict__ z) {
    int j = blockIdx.x * 256 + threadIdx.x;
    z[j] = input[j];
}

// --- Kernel 2: partial matvec: z[j] += sum_i yin[i]*(w[i,j] + alpha[i,j]*hebb[i,j]) ---
// R1 geometry: grid = (8 col-tiles, 512 row-chunks), block = 256, 4 cols/thread,
// 16 rows/block. Delta vs R1: NONTEMPORAL loads on w/alpha/hebb to bypass the
// L3 service path (suspected ~2 TB/s wall on the L3-hit portion).
__global__ __launch_bounds__(256) void matvec_partial(
    const float* __restrict__ yin,
    const float* __restrict__ w,
    const float* __restrict__ alpha,
    const float* __restrict__ hebb,
    float* __restrict__ z)
{
    const int j0 = blockIdx.x * 1024 + threadIdx.x * 4;
    const int i0 = blockIdx.y * 16;

    v4f s = {0.f, 0.f, 0.f, 0.f};
#pragma unroll 4
    for (int r = 0; r < 16; ++r) {
        const int i = i0 + r;
        const float y = yin[i];  // uniform per block iter -> scalar load
        const size_t base = (size_t)i * NN + (size_t)j0;
        const v4f wv = nt_load4(w + base);
        const v4f av = nt_load4(alpha + base);
        const v4f hv = nt_load4(hebb + base);
        s.x = fmaf(y, fmaf(av.x, hv.x, wv.x), s.x);
        s.y = fmaf(y, fmaf(av.y, hv.y, wv.y), s.y);
        s.z = fmaf(y, fmaf(av.z, hv.z, wv.z), s.z);
        s.w = fmaf(y, fmaf(av.w, hv.w, wv.w), s.w);
    }
    atomicAdd(&z[j0 + 0], s.x);
    atomicAdd(&z[j0 + 1], s.y);
    atomicAdd(&z[j0 + 2], s.z);
    atomicAdd(&z[j0 + 3], s.w);
}

// --- Kernel 3: yout[j] = tanh(z[j]) ---
__global__ __launch_bounds__(256) void tanh_k(const float* __restrict__ z,
                                              float* __restrict__ yout) {
    int j = blockIdx.x * 256 + threadIdx.x;
    yout[j] = tanhf(z[j]);
}

// --- Kernel 4: hebb_new[i,j] = (1-eta)*hebb[i,j] + eta*yin[i]*yout[j] ---
// 16384 blocks x 256 threads, 4 float4 per thread (coalesced within block)
__global__ __launch_bounds__(256) void hebb_update(
    const float* __restrict__ hebb,
    const float* __restrict__ yin,
    const float* __restrict__ yout,
    const float* __restrict__ eta_p,
    float* __restrict__ hebb_out)
{
    const float eta = eta_p[0];
    const float om = 1.0f - eta;
    const size_t f0 = (size_t)blockIdx.x * 1024 + threadIdx.x;
#pragma unroll
    for (int k = 0; k < 4; ++k) {
        const size_t f = f0 + (size_t)k * 256;   // float4 index
        const size_t i = f >> 11;                // row (2048 float4 per row)
        const size_t j = (f & 2047) * 4;         // col
        const float ye = eta * yin[i];
        const float4 h  = *(const float4*)(hebb + i * NN + j);
        const float4 yo = *(const float4*)(yout + j);
        float4 o;
        o.x = fmaf(om, h.x, ye * yo.x);
        o.y = fmaf(om, h.y, ye * yo.y);
        o.z = fmaf(om, h.z, ye * yo.z);
        o.w = fmaf(om, h.w, ye * yo.w);
        *(float4*)(hebb_out + i * NN + j) = o;
    }
}

extern "C" void kernel_launch(void* const* d_in, const int* in_sizes, int n_in,
                              void* d_out, int out_size, void* d_ws, size_t ws_size,
                              hipStream_t stream) {
    const float* input = (const float*)d_in[0];   // [1, N]
    const float* yin   = (const float*)d_in[1];   // [1, N]
    const float* hebb  = (const float*)d_in[2];   // [N, N]
    const float* w     = (const float*)d_in[3];   // [N, N]
    const float* alpha = (const float*)d_in[4];   // [N, N]
    const float* eta   = (const float*)d_in[5];   // [1]

    float* yout_out = (float*)d_out;              // first N floats
    float* hebb_out = yout_out + NN;              // next N*N floats
    float* z = (float*)d_ws;                      // N floats scratch

    init_z<<<NN / 256, 256, 0, stream>>>(input, z);
    matvec_partial<<<dim3(8, 512), 256, 0, stream>>>(yin, w, alpha, hebb, z);
    tanh_k<<<NN / 256, 256, 0, stream>>>(z, yout_out);
    hebb_update<<<(NN * (size_t)NN) / 4096, 256, 0, stream>>>(hebb, yin, yout_out, eta, hebb_out);
}

// Round 4
// 762.470 us; speedup vs baseline: 1.0834x; 1.0385x over previous
//
#include <hip/hip_runtime.h>

#define NN 8192

typedef float v4f __attribute__((ext_vector_type(4)));

__device__ __forceinline__ v4f nt_load4(const float* p) {
    return __builtin_nontemporal_load((const v4f*)p);
}
__device__ __forceinline__ void nt_store4(float* p, v4f v) {
    __builtin_nontemporal_store(v, (v4f*)p);
}

// --- Kernel 1: z[j] = input[j] (workspace is poisoned each launch) ---
__global__ __launch_bounds__(256) void init_z(const float* __restrict__ input,
                                              float* __restrict__ z) {
    int j = blockIdx.x * 256 + threadIdx.x;
    z[j] = input[j];
}

// --- Kernel 2: partial matvec: z[j] += sum_i yin[i]*(w[i,j] + alpha[i,j]*hebb[i,j]) ---
// grid = (8 col-tiles, 512 row-chunks), block = 256, 4 cols/thread, 16 rows/block.
// Cache policy by reuse distance: w/alpha read ONCE per iter -> nontemporal
// (no L2/L3 allocate). hebb read TWICE (here + hebb_update) and is exactly
// L3-sized (256 MB) -> regular load so it becomes/stays L3-resident.
__global__ __launch_bounds__(256) void matvec_partial(
    const float* __restrict__ yin,
    const float* __restrict__ w,
    const float* __restrict__ alpha,
    const float* __restrict__ hebb,
    float* __restrict__ z)
{
    const int j0 = blockIdx.x * 1024 + threadIdx.x * 4;
    const int i0 = blockIdx.y * 16;

    v4f s = {0.f, 0.f, 0.f, 0.f};
#pragma unroll 4
    for (int r = 0; r < 16; ++r) {
        const int i = i0 + r;
        const float y = yin[i];  // uniform per block iter -> scalar load
        const size_t base = (size_t)i * NN + (size_t)j0;
        const v4f wv = nt_load4(w + base);
        const v4f av = nt_load4(alpha + base);
        const v4f hv = *(const v4f*)(hebb + base);   // regular: keep in L3
        s.x = fmaf(y, fmaf(av.x, hv.x, wv.x), s.x);
        s.y = fmaf(y, fmaf(av.y, hv.y, wv.y), s.y);
        s.z = fmaf(y, fmaf(av.z, hv.z, wv.z), s.z);
        s.w = fmaf(y, fmaf(av.w, hv.w, wv.w), s.w);
    }
    atomicAdd(&z[j0 + 0], s.x);
    atomicAdd(&z[j0 + 1], s.y);
    atomicAdd(&z[j0 + 2], s.z);
    atomicAdd(&z[j0 + 3], s.w);
}

// --- Kernel 3: yout[j] = tanh(z[j]) ---
__global__ __launch_bounds__(256) void tanh_k(const float* __restrict__ z,
                                              float* __restrict__ yout) {
    int j = blockIdx.x * 256 + threadIdx.x;
    yout[j] = tanhf(z[j]);
}

// --- Kernel 4: hebb_new[i,j] = (1-eta)*hebb[i,j] + eta*yin[i]*yout[j] ---
// 16384 blocks x 256 threads, 4 float4 per thread (coalesced within block).
// hebb read: regular (should be L3-hit after matvec). hebb_out store:
// nontemporal -- written once, never read; don't evict hebb with write-allocate.
__global__ __launch_bounds__(256) void hebb_update(
    const float* __restrict__ hebb,
    const float* __restrict__ yin,
    const float* __restrict__ yout,
    const float* __restrict__ eta_p,
    float* __restrict__ hebb_out)
{
    const float eta = eta_p[0];
    const float om = 1.0f - eta;
    const size_t f0 = (size_t)blockIdx.x * 1024 + threadIdx.x;
#pragma unroll
    for (int k = 0; k < 4; ++k) {
        const size_t f = f0 + (size_t)k * 256;   // float4 index
        const size_t i = f >> 11;                // row (2048 float4 per row)
        const size_t j = (f & 2047) * 4;         // col
        const float ye = eta * yin[i];
        const v4f h  = *(const v4f*)(hebb + i * NN + j);
        const v4f yo = *(const v4f*)(yout + j);
        v4f o;
        o.x = fmaf(om, h.x, ye * yo.x);
        o.y = fmaf(om, h.y, ye * yo.y);
        o.z = fmaf(om, h.z, ye * yo.z);
        o.w = fmaf(om, h.w, ye * yo.w);
        nt_store4(hebb_out + i * NN + j, o);
    }
}

extern "C" void kernel_launch(void* const* d_in, const int* in_sizes, int n_in,
                              void* d_out, int out_size, void* d_ws, size_t ws_size,
                              hipStream_t stream) {
    const float* input = (const float*)d_in[0];   // [1, N]
    const float* yin   = (const float*)d_in[1];   // [1, N]
    const float* hebb  = (const float*)d_in[2];   // [N, N]
    const float* w     = (const float*)d_in[3];   // [N, N]
    const float* alpha = (const float*)d_in[4];   // [N, N]
    const float* eta   = (const float*)d_in[5];   // [1]

    float* yout_out = (float*)d_out;              // first N floats
    float* hebb_out = yout_out + NN;              // next N*N floats
    float* z = (float*)d_ws;                      // N floats scratch

    init_z<<<NN / 256, 256, 0, stream>>>(input, z);
    matvec_partial<<<dim3(8, 512), 256, 0, stream>>>(yin, w, alpha, hebb, z);
    tanh_k<<<NN / 256, 256, 0, stream>>>(z, yout_out);
    hebb_update<<<(NN * (size_t)NN) / 4096, 256, 0, stream>>>(hebb, yin, yout_out, eta, hebb_out);
}